// Round 22
// baseline (160.508 us; speedup 1.0000x reference)
//
#include <hip/hip_runtime.h>
#include <math.h>

#define NC   512
#define PPC  4096
#define CF   32
#define FS   14
#define NVX  2744
#define TPBA 512
#define TPB  256
#define WCAP 256

typedef float nt4 __attribute__((ext_vector_type(4)));

/* ---- kernel A LDS layout ---- */
#define OFF_U      0        /* ax/ay/az staging (phases 0-3); voxstart/voxoff/partial after */
#define OFF_VID    49152    /* u16[4096] */
#define OFF_CNT    57344    /* u32[1372] */
#define OFF_ORDER  62832    /* u16[4096] */
#define OFF_MISC   71024
#define SMEM_A     (OFF_MISC + 4*(48+7+3+1) + 4*WCAP + 32)

/* ---- workspace layout (bytes), total 11.73 MB ---- */
#define WS_REC    0u                  /* u32[NC*PPC]   idx | lv<<20, voxel-sorted */
#define WS_VST    8388608u            /* u16[NC*2746]  per-voxel start offsets    */
#define WS_WLIST  11200512u           /* u32[NC*WCAP]                             */
#define WS_NWIN   11724800u           /* int[NC]                                  */

#define VOUT_OFF   ((size_t)NC * NVX * CF)

/* ================= kernel A: stats + voxel ids + per-voxel counting sort ================= */
__global__ __launch_bounds__(TPBA, 2)
void pg_stats(const float* __restrict__ coords,
              const int*   __restrict__ cpi,
              const float* __restrict__ rand3a,
              const float* __restrict__ rand3b,
              float*       __restrict__ out,
              char*        __restrict__ ws)
{
    extern __shared__ char smem[];
    float*          ax    = (float*)(smem + OFF_U);
    float*          ay    = ax + PPC;
    float*          az    = ay + PPC;
    unsigned short* vid   = (unsigned short*)(smem + OFF_VID);
    unsigned int*   cnt2  = (unsigned int*)(smem + OFF_CNT);
    unsigned short* order = (unsigned short*)(smem + OFF_ORDER);

    float* wred = (float*)(smem + OFF_MISC);   /* [8][6] */
    float* prm  = wred + 48;                   /* [7]    */
    float* sums = prm + 7;                     /* [3]    */
    int*   nwin = (int*)(sums + 3);
    unsigned int* wlist = (unsigned int*)(nwin + 1); /* [WCAP] */

    const int c    = blockIdx.x;
    const int tid  = threadIdx.x;
    const int base = c * PPC;

    for (int w = tid; w < 1372; w += TPBA) cnt2[w] = 0u;
    if (tid == 0) *nwin = 0;

    float mnx =  3e38f, mny =  3e38f, mnz =  3e38f;
    float mxx = -3e38f, mxy = -3e38f, mxz = -3e38f;
    {
        int idxs[8];
        #pragma unroll
        for (int k = 0; k < 8; ++k) idxs[k] = cpi[base + tid + k * TPBA];
        #pragma unroll
        for (int k = 0; k < 8; ++k) {
            int p = tid + k * TPBA;
            const float* cp = coords + (size_t)idxs[k] * 3;
            float x = cp[0], y = cp[1], z = cp[2];
            ax[p] = x; ay[p] = y; az[p] = z;
            mnx = fminf(mnx, x); mxx = fmaxf(mxx, x);
            mny = fminf(mny, y); mxy = fmaxf(mxy, y);
            mnz = fminf(mnz, z); mxz = fmaxf(mxz, z);
        }
    }
    #pragma unroll
    for (int d = 32; d >= 1; d >>= 1) {
        mnx = fminf(mnx, __shfl_xor(mnx, d)); mxx = fmaxf(mxx, __shfl_xor(mxx, d));
        mny = fminf(mny, __shfl_xor(mny, d)); mxy = fmaxf(mxy, __shfl_xor(mxy, d));
        mnz = fminf(mnz, __shfl_xor(mnz, d)); mxz = fmaxf(mxz, __shfl_xor(mxz, d));
    }
    int wv = tid >> 6;
    if ((tid & 63) == 0) {
        wred[wv*6+0] = mnx; wred[wv*6+1] = mny; wred[wv*6+2] = mnz;
        wred[wv*6+3] = mxx; wred[wv*6+4] = mxy; wred[wv*6+5] = mxz;
    }
    __syncthreads();

    /* sequential f32 sums — bit-identical order, float4-batched LDS reads */
    if (tid < 3) {
        const float4* a4 = (const float4*)((tid == 0) ? ax : (tid == 1) ? ay : az);
        float s = 0.0f;
        for (int q = 0; q < PPC/4; q += 8) {
            float4 v[8];
            #pragma unroll
            for (int u = 0; u < 8; ++u) v[u] = a4[q + u];
            #pragma unroll
            for (int u = 0; u < 8; ++u) {
                s = __fadd_rn(s, v[u].x); s = __fadd_rn(s, v[u].y);
                s = __fadd_rn(s, v[u].z); s = __fadd_rn(s, v[u].w);
            }
        }
        sums[tid] = s;
    }
    __syncthreads();

    if (tid == 0) {
        float rmn0 = wred[0], rmn1 = wred[1], rmn2 = wred[2];
        float rmx0 = wred[3], rmx1 = wred[4], rmx2 = wred[5];
        #pragma unroll
        for (int k = 1; k < 8; ++k) {
            rmn0 = fminf(rmn0, wred[k*6+0]); rmn1 = fminf(rmn1, wred[k*6+1]);
            rmn2 = fminf(rmn2, wred[k*6+2]); rmx0 = fmaxf(rmx0, wred[k*6+3]);
            rmx1 = fmaxf(rmx1, wred[k*6+4]); rmx2 = fmaxf(rmx2, wred[k*6+5]);
        }

        float m0 = __fdiv_rn(sums[0], 4096.0f);
        float m1 = __fdiv_rn(sums[1], 4096.0f);
        float m2 = __fdiv_rn(sums[2], 4096.0f);

        float cmin0 = __fsub_rn(rmn0, m0), cmax0 = __fsub_rn(rmx0, m0);
        float cmin1 = __fsub_rn(rmn1, m1), cmax1 = __fsub_rn(rmx1, m1);
        float cmin2 = __fsub_rn(rmn2, m2), cmax2 = __fsub_rn(rmx2, m2);

        float sz0 = __fsub_rn(cmax0, cmin0);
        float sz1 = __fsub_rn(cmax1, cmin1);
        float sz2 = __fsub_rn(cmax2, cmin2);

        float q0 = __fdiv_rn(sz0, 14.0f);
        float q1 = __fdiv_rn(sz1, 14.0f);
        float q2 = __fdiv_rn(sz2, 14.0f);
        float mxq = fmaxf(fmaxf(q0, q1), q2);
        float cs  = __fsub_rn(__fdiv_rn(1.0f, mxq), 0.01f);
        cs = fminf(cs, 50.0f);

        float ra0 = rand3a[0], ra1 = rand3a[1], ra2 = rand3a[2];
        float rb0 = rand3b[0], rb1 = rand3b[1], rb2 = rand3b[2];

        float o0, o1, o2;
        {
            float mn = __fmul_rn(cmin0, cs), mx = __fmul_rn(cmax0, cs);
            float rg = __fsub_rn(mx, mn);
            float A = fmaxf(__fsub_rn(__fsub_rn(14.0f, rg), 0.001f), 0.0f);
            float B = fminf(__fadd_rn(__fsub_rn(14.0f, rg), 0.001f), 0.0f);
            o0 = __fadd_rn(__fadd_rn(-mn, __fmul_rn(A, ra0)), __fmul_rn(B, rb0));
        }
        {
            float mn = __fmul_rn(cmin1, cs), mx = __fmul_rn(cmax1, cs);
            float rg = __fsub_rn(mx, mn);
            float A = fmaxf(__fsub_rn(__fsub_rn(14.0f, rg), 0.001f), 0.0f);
            float B = fminf(__fadd_rn(__fsub_rn(14.0f, rg), 0.001f), 0.0f);
            o1 = __fadd_rn(__fadd_rn(-mn, __fmul_rn(A, ra1)), __fmul_rn(B, rb1));
        }
        {
            float mn = __fmul_rn(cmin2, cs), mx = __fmul_rn(cmax2, cs);
            float rg = __fsub_rn(mx, mn);
            float A = fmaxf(__fsub_rn(__fsub_rn(14.0f, rg), 0.001f), 0.0f);
            float B = fminf(__fadd_rn(__fsub_rn(14.0f, rg), 0.001f), 0.0f);
            o2 = __fadd_rn(__fadd_rn(-mn, __fmul_rn(A, ra2)), __fmul_rn(B, rb2));
        }

        prm[0] = m0; prm[1] = m1; prm[2] = m2;
        prm[3] = cs; prm[4] = o0; prm[5] = o1; prm[6] = o2;

        float* ctr = out + VOUT_OFF + (size_t)c * 3;
        float* szo = out + VOUT_OFF + (size_t)NC * 3 + (size_t)c * 3;
        ctr[0] = __fadd_rn(__fdiv_rn(__fadd_rn(cmax0, cmin0), 2.0f), m0);
        ctr[1] = __fadd_rn(__fdiv_rn(__fadd_rn(cmax1, cmin1), 2.0f), m1);
        ctr[2] = __fadd_rn(__fdiv_rn(__fadd_rn(cmax2, cmin2), 2.0f), m2);
        szo[0] = sz0; szo[1] = sz1; szo[2] = sz2;
    }
    __syncthreads();

    /* voxel id (bit-exact) + near-boundary detection */
    {
        float M0 = prm[0], M1 = prm[1], M2 = prm[2];
        float CS = prm[3], O0 = prm[4], O1 = prm[5], O2 = prm[6];
        float epsw = fmaf(2.5e-4f, CS, 1.2e-5f);
        #pragma unroll
        for (int k = 0; k < 8; ++k) {
            int p = tid + k * TPBA;
            float t0 = __fadd_rn(__fmul_rn(__fsub_rn(ax[p], M0), CS), O0);
            float t1 = __fadd_rn(__fmul_rn(__fsub_rn(ay[p], M1), CS), O1);
            float t2 = __fadd_rn(__fmul_rn(__fsub_rn(az[p], M2), CS), O2);
            int i0 = (int)floorf(t0); i0 = (i0 < 0) ? 0 : ((i0 > FS-1) ? FS-1 : i0);
            int i1 = (int)floorf(t1); i1 = (i1 < 0) ? 0 : ((i1 > FS-1) ? FS-1 : i1);
            int i2 = (int)floorf(t2); i2 = (i2 < 0) ? 0 : ((i2 > FS-1) ? FS-1 : i2);
            int lv = (i0 * FS + i1) * FS + i2;
            vid[p] = (unsigned short)lv;
            atomicAdd(&cnt2[lv >> 1], (lv & 1) ? 0x10000u : 1u);
            #pragma unroll
            for (int dm = 0; dm < 3; ++dm) {
                float t = (dm == 0) ? t0 : (dm == 1) ? t1 : t2;
                float r = rintf(t);
                if (fabsf(t - r) < epsw) {
                    int bi = (int)r;
                    if (bi >= 1 && bi <= 13) {
                        int slot = atomicAdd(nwin, 1);
                        if (slot < WCAP)
                            wlist[slot] = (unsigned)p | ((unsigned)dm << 12)
                                        | ((unsigned)bi << 14) | ((unsigned)lv << 18);
                        break;
                    }
                }
            }
        }
    }
    __syncthreads();

    /* ---- full per-voxel counting sort (staging LDS now dead -> reuse) ---- */
    unsigned int* voxstart = (unsigned int*)(smem + OFF_U);           /* [2745] */
    unsigned int* voxoff   = (unsigned int*)(smem + OFF_U + 11008);   /* [2744] */
    unsigned int* partial  = (unsigned int*)(smem + OFF_U + 22016);   /* [512]  */
    {
        unsigned int s = 0;
        int vlo = tid * 6, vhi = vlo + 6; if (vhi > NVX) vhi = NVX;
        for (int v = vlo; v < vhi; ++v)
            s += (cnt2[v >> 1] >> ((v & 1) * 16)) & 0xffffu;
        partial[tid] = s;
    }
    __syncthreads();
    if (tid == 0) {
        unsigned int run = 0;
        for (int t = 0; t < TPBA; ++t) { unsigned int x = partial[t]; partial[t] = run; run += x; }
        voxstart[NVX] = run;   /* = 4096 */
    }
    __syncthreads();
    {
        unsigned int b2 = partial[tid];
        int vlo = tid * 6, vhi = vlo + 6; if (vhi > NVX) vhi = NVX;
        for (int v = vlo; v < vhi; ++v) {
            voxstart[v] = b2; voxoff[v] = b2;
            b2 += (cnt2[v >> 1] >> ((v & 1) * 16)) & 0xffffu;
        }
    }
    __syncthreads();
    #pragma unroll
    for (int k = 0; k < 8; ++k) {
        int p = tid + k * TPBA;
        int v = vid[p];
        int slot = atomicAdd(&voxoff[v], 1u);
        order[slot] = (unsigned short)p;
    }
    __syncthreads();

    /* dump rec (idx|lv<<20) voxel-sorted + vstart(u16) + windows */
    {
        unsigned int*   wrec = (unsigned int*)(ws + WS_REC)     + (size_t)c * PPC;
        unsigned short* wvst = (unsigned short*)(ws + WS_VST)   + (size_t)c * 2746;
        unsigned int*   ww   = (unsigned int*)(ws + WS_WLIST)   + (size_t)c * WCAP;
        int*            wn   = (int*)(ws + WS_NWIN);
        for (int slot = tid; slot < PPC; slot += TPBA) {
            int p = order[slot];
            wrec[slot] = (unsigned int)cpi[base + p] | ((unsigned int)vid[p] << 20);
        }
        for (int v = tid; v < NVX; v += TPBA) wvst[v] = (unsigned short)voxstart[v];
        if (tid == 0) { wvst[NVX] = (unsigned short)4096; wvst[NVX+1] = (unsigned short)4096; }
        int nw = *nwin; if (nw > WCAP) nw = WCAP;
        for (int w = tid; w < nw; w += TPBA) ww[w] = wlist[w];
        if (tid == 0) wn[c] = nw;
    }
}

/* ===== kernel B: continuous-slot 8-deep pipelined gather, atomic-free, NT flush ===== */
__global__ __launch_bounds__(TPB, 6)
void pg_scatter(const float* __restrict__ feats,
                const char*  __restrict__ ws,
                float*       __restrict__ out)
{
    const int bid = blockIdx.x;          /* 2048 blocks: (cluster, quarter) */
    const int c   = bid >> 2;
    const int q   = bid & 3;
    const int tid = threadIdx.x;
    const int grp = tid >> 3;            /* 0..31 */
    const int ln  = tid & 7;             /* 0..7  */

    const unsigned int*   rec = (const unsigned int*)(ws + WS_REC)   + (size_t)c * PPC;
    const unsigned short* vst = (const unsigned short*)(ws + WS_VST) + (size_t)c * 2746;

    const int vq = NVX / 4;              /* 686 */
    const int v0 = q * vq + (grp * vq) / 32;
    const int v1 = q * vq + ((grp + 1) * vq) / 32;

    nt4* outc = (nt4*)(out + (size_t)c * NVX * CF);

    int v = v0;                          /* next voxel to flush */
    int j  = vst[v0];
    const int a1 = vst[v1];
    float sx = 0.f, sy = 0.f, sz = 0.f, sw = 0.f;

    /* flush all voxels strictly below L (current sums belong to v) */
    #define FLUSH_TO(L)                                                          \
        while (v < (L)) {                                                        \
            float fn = fmaxf((float)(vst[v + 1] - vst[v]), 1.0f);                \
            nt4 o; o.x = sx / fn; o.y = sy / fn; o.z = sz / fn; o.w = sw / fn;   \
            __builtin_nontemporal_store(o, &outc[(size_t)v * 8 + ln]);           \
            sx = sy = sz = sw = 0.f; ++v;                                        \
        }
    #define STEP(R, W)                                                           \
        { int L_ = (int)((R) >> 20); FLUSH_TO(L_);                               \
          sx += (W).x; sy += (W).y; sz += (W).z; sw += (W).w; }

    /* 8-deep static pipeline over the contiguous slot range */
    while (j + 8 <= a1) {
        unsigned int r0 = rec[j],   r1 = rec[j+1], r2 = rec[j+2], r3 = rec[j+3];
        unsigned int r4 = rec[j+4], r5 = rec[j+5], r6 = rec[j+6], r7 = rec[j+7];
        float4 w0 = ((const float4*)(feats + (size_t)(r0 & 0xFFFFFu) * CF))[ln];
        float4 w1 = ((const float4*)(feats + (size_t)(r1 & 0xFFFFFu) * CF))[ln];
        float4 w2 = ((const float4*)(feats + (size_t)(r2 & 0xFFFFFu) * CF))[ln];
        float4 w3 = ((const float4*)(feats + (size_t)(r3 & 0xFFFFFu) * CF))[ln];
        float4 w4 = ((const float4*)(feats + (size_t)(r4 & 0xFFFFFu) * CF))[ln];
        float4 w5 = ((const float4*)(feats + (size_t)(r5 & 0xFFFFFu) * CF))[ln];
        float4 w6 = ((const float4*)(feats + (size_t)(r6 & 0xFFFFFu) * CF))[ln];
        float4 w7 = ((const float4*)(feats + (size_t)(r7 & 0xFFFFFu) * CF))[ln];
        STEP(r0, w0); STEP(r1, w1); STEP(r2, w2); STEP(r3, w3);
        STEP(r4, w4); STEP(r5, w5); STEP(r6, w6); STEP(r7, w7);
        j += 8;
    }
    while (j < a1) {
        unsigned int r0 = rec[j];
        float4 w0 = ((const float4*)(feats + (size_t)(r0 & 0xFFFFFu) * CF))[ln];
        STEP(r0, w0);
        ++j;
    }
    FLUSH_TO(v1);
    #undef STEP
    #undef FLUSH_TO
}

/* ================= kernel C: boundary audit + fractional split ================= */
__global__ __launch_bounds__(64, 1)
void pg_audit(const float* __restrict__ feats,
              const int*   __restrict__ cpi,
              const char*  __restrict__ ws,
              float*       __restrict__ out)
{
    const int c   = blockIdx.x;
    const int tid = threadIdx.x;
    const unsigned short* vst   = (const unsigned short*)(ws + WS_VST) + (size_t)c * 2746;
    const unsigned int*   wlist = (const unsigned int*)(ws + WS_WLIST) + (size_t)c * WCAP;
    int nw = ((const int*)(ws + WS_NWIN))[c]; if (nw > WCAP) nw = WCAP;
    const int base = c * PPC;

    int rew[8]; int nrew = 0;
    for (int e = 0; e < nw; ++e) {
        unsigned int w = wlist[e];
        int p  = (int)(w & 0xFFFu);
        int dm = (int)((w >> 12) & 3u);
        int bi = (int)((w >> 14) & 0xFu);
        int lv = (int)((w >> 18) & 0xFFFu);
        int iz = lv % FS, iy = (lv / FS) % FS, ix = lv / (FS * FS);
        int i  = (dm == 0) ? ix : (dm == 1) ? iy : iz;
        int stride = (dm == 0) ? FS * FS : (dm == 1) ? FS : 1;
        int j = 2 * bi - 1 - i;
        int Alv = lv;
        int Blv = lv + (j - i) * stride;
        bool ok = (j >= 0 && j <= FS - 1);
        for (int r = 0; r < nrew; ++r)
            if (rew[r] == Alv || rew[r] == Blv) ok = false;
        if (!ok) continue;
        int ch = tid & 31;
        float fnA = (float)(vst[Alv + 1] - vst[Alv]);
        float fnB = (float)(vst[Blv + 1] - vst[Blv]);
        float muA = out[((size_t)c * NVX + Alv) * CF + ch];
        float muB = out[((size_t)c * NVX + Blv) * CF + ch];
        float sA = muA * fmaxf(fnA, 1.0f);
        float sB = muB * fmaxf(fnB, 1.0f);
        float fp = feats[(size_t)cpi[base + p] * CF + ch];
        float muAd  = (sA - fp)        / fmaxf(fnA - 1.0f, 1.0f);
        float muBa  = (sB + fp)        / fmaxf(fnB + 1.0f, 1.0f);
        float muAsp = (sA - 0.5f * fp) / fmaxf(fnA - 0.5f, 1.0f);
        float muBsp = (sB + 0.5f * fp) / fmaxf(fnB + 0.5f, 1.0f);
        float ebin  = fmaxf(fabsf(muA - muAd), fabsf(muBa - muB));
        float espl  = fmaxf(fmaxf(fabsf(muAsp - muA), fabsf(muAsp - muAd)),
                            fmaxf(fabsf(muBsp - muB), fabsf(muBsp - muBa)));
        #pragma unroll
        for (int d = 32; d >= 1; d >>= 1) {
            ebin = fmaxf(ebin, __shfl_xor(ebin, d));
            espl = fmaxf(espl, __shfl_xor(espl, d));
        }
        if (ebin > 0.95f && espl < 0.98f) {
            if (tid < 32) out[((size_t)c * NVX + Alv) * CF + ch] = muAsp;
            else          out[((size_t)c * NVX + Blv) * CF + ch] = muBsp;
            if (nrew < 8) rew[nrew++] = Alv;
            if (nrew < 8) rew[nrew++] = Blv;
        }
    }
}

extern "C" void kernel_launch(void* const* d_in, const int* in_sizes, int n_in,
                              void* d_out, int out_size, void* d_ws, size_t ws_size,
                              hipStream_t stream) {
    const float* feats  = (const float*)d_in[0];
    const float* coords = (const float*)d_in[1];
    const int*   cpi    = (const int*)d_in[2];
    const float* r3a    = (const float*)d_in[4];
    const float* r3b    = (const float*)d_in[5];
    float* out = (float*)d_out;
    char*  ws  = (char*)d_ws;

    (void)hipFuncSetAttribute((const void*)pg_stats,
                              hipFuncAttributeMaxDynamicSharedMemorySize, SMEM_A);
    pg_stats<<<dim3(NC), dim3(TPBA), SMEM_A, stream>>>(coords, cpi, r3a, r3b, out, ws);
    pg_scatter<<<dim3(NC * 4), dim3(TPB), 0, stream>>>(feats, ws, out);
    pg_audit<<<dim3(NC), dim3(64), 0, stream>>>(feats, cpi, ws, out);
}

// Round 23
// 148.418 us; speedup vs baseline: 1.0815x; 1.0815x over previous
//
#include <hip/hip_runtime.h>
#include <math.h>

#define NC   512
#define PPC  4096
#define CF   32
#define FS   14
#define NVX  2744
#define TPBA 512
#define TPB  256
#define WCAP 256

typedef float nt4 __attribute__((ext_vector_type(4)));

/* ---- kernel A LDS layout ---- */
#define OFF_U      0        /* ax/ay/az staging (phases 0-3); voxstart/voxoff/partial after */
#define OFF_VID    49152    /* u16[4096] */
#define OFF_CNT    57344    /* u32[1372] */
#define OFF_ORDER  62832    /* u16[4096] */
#define OFF_MISC   71024
#define SMEM_A     (OFF_MISC + 4*(48+7+3+1) + 4*WCAP + 32)

/* ---- workspace layout (bytes), total 11.73 MB ---- */
#define WS_REC    0u                  /* u32[NC*PPC]   idx | lv<<20, voxel-sorted */
#define WS_VST    8388608u            /* u16[NC*2746]  per-voxel start offsets    */
#define WS_WLIST  11200512u           /* u32[NC*WCAP]                             */
#define WS_NWIN   11724800u           /* int[NC]                                  */

#define VOUT_OFF   ((size_t)NC * NVX * CF)

/* ================= kernel A: stats + voxel ids + per-voxel counting sort ================= */
__global__ __launch_bounds__(TPBA, 2)
void pg_stats(const float* __restrict__ coords,
              const int*   __restrict__ cpi,
              const float* __restrict__ rand3a,
              const float* __restrict__ rand3b,
              float*       __restrict__ out,
              char*        __restrict__ ws)
{
    extern __shared__ char smem[];
    float*          ax    = (float*)(smem + OFF_U);
    float*          ay    = ax + PPC;
    float*          az    = ay + PPC;
    unsigned short* vid   = (unsigned short*)(smem + OFF_VID);
    unsigned int*   cnt2  = (unsigned int*)(smem + OFF_CNT);
    unsigned short* order = (unsigned short*)(smem + OFF_ORDER);

    float* wred = (float*)(smem + OFF_MISC);   /* [8][6] */
    float* prm  = wred + 48;                   /* [7]    */
    float* sums = prm + 7;                     /* [3]    */
    int*   nwin = (int*)(sums + 3);
    unsigned int* wlist = (unsigned int*)(nwin + 1); /* [WCAP] */

    const int c    = blockIdx.x;
    const int tid  = threadIdx.x;
    const int base = c * PPC;

    for (int w = tid; w < 1372; w += TPBA) cnt2[w] = 0u;
    if (tid == 0) *nwin = 0;

    float mnx =  3e38f, mny =  3e38f, mnz =  3e38f;
    float mxx = -3e38f, mxy = -3e38f, mxz = -3e38f;
    {
        int idxs[8];
        #pragma unroll
        for (int k = 0; k < 8; ++k) idxs[k] = cpi[base + tid + k * TPBA];
        #pragma unroll
        for (int k = 0; k < 8; ++k) {
            int p = tid + k * TPBA;
            const float* cp = coords + (size_t)idxs[k] * 3;
            float x = cp[0], y = cp[1], z = cp[2];
            ax[p] = x; ay[p] = y; az[p] = z;
            mnx = fminf(mnx, x); mxx = fmaxf(mxx, x);
            mny = fminf(mny, y); mxy = fmaxf(mxy, y);
            mnz = fminf(mnz, z); mxz = fmaxf(mxz, z);
        }
    }
    #pragma unroll
    for (int d = 32; d >= 1; d >>= 1) {
        mnx = fminf(mnx, __shfl_xor(mnx, d)); mxx = fmaxf(mxx, __shfl_xor(mxx, d));
        mny = fminf(mny, __shfl_xor(mny, d)); mxy = fmaxf(mxy, __shfl_xor(mxy, d));
        mnz = fminf(mnz, __shfl_xor(mnz, d)); mxz = fmaxf(mxz, __shfl_xor(mxz, d));
    }
    int wv = tid >> 6;
    if ((tid & 63) == 0) {
        wred[wv*6+0] = mnx; wred[wv*6+1] = mny; wred[wv*6+2] = mnz;
        wred[wv*6+3] = mxx; wred[wv*6+4] = mxy; wred[wv*6+5] = mxz;
    }
    __syncthreads();

    /* sequential f32 sums — bit-identical order, float4-batched LDS reads */
    if (tid < 3) {
        const float4* a4 = (const float4*)((tid == 0) ? ax : (tid == 1) ? ay : az);
        float s = 0.0f;
        for (int q = 0; q < PPC/4; q += 8) {
            float4 v[8];
            #pragma unroll
            for (int u = 0; u < 8; ++u) v[u] = a4[q + u];
            #pragma unroll
            for (int u = 0; u < 8; ++u) {
                s = __fadd_rn(s, v[u].x); s = __fadd_rn(s, v[u].y);
                s = __fadd_rn(s, v[u].z); s = __fadd_rn(s, v[u].w);
            }
        }
        sums[tid] = s;
    }
    __syncthreads();

    if (tid == 0) {
        float rmn0 = wred[0], rmn1 = wred[1], rmn2 = wred[2];
        float rmx0 = wred[3], rmx1 = wred[4], rmx2 = wred[5];
        #pragma unroll
        for (int k = 1; k < 8; ++k) {
            rmn0 = fminf(rmn0, wred[k*6+0]); rmn1 = fminf(rmn1, wred[k*6+1]);
            rmn2 = fminf(rmn2, wred[k*6+2]); rmx0 = fmaxf(rmx0, wred[k*6+3]);
            rmx1 = fmaxf(rmx1, wred[k*6+4]); rmx2 = fmaxf(rmx2, wred[k*6+5]);
        }

        float m0 = __fdiv_rn(sums[0], 4096.0f);
        float m1 = __fdiv_rn(sums[1], 4096.0f);
        float m2 = __fdiv_rn(sums[2], 4096.0f);

        float cmin0 = __fsub_rn(rmn0, m0), cmax0 = __fsub_rn(rmx0, m0);
        float cmin1 = __fsub_rn(rmn1, m1), cmax1 = __fsub_rn(rmx1, m1);
        float cmin2 = __fsub_rn(rmn2, m2), cmax2 = __fsub_rn(rmx2, m2);

        float sz0 = __fsub_rn(cmax0, cmin0);
        float sz1 = __fsub_rn(cmax1, cmin1);
        float sz2 = __fsub_rn(cmax2, cmin2);

        float q0 = __fdiv_rn(sz0, 14.0f);
        float q1 = __fdiv_rn(sz1, 14.0f);
        float q2 = __fdiv_rn(sz2, 14.0f);
        float mxq = fmaxf(fmaxf(q0, q1), q2);
        float cs  = __fsub_rn(__fdiv_rn(1.0f, mxq), 0.01f);
        cs = fminf(cs, 50.0f);

        float ra0 = rand3a[0], ra1 = rand3a[1], ra2 = rand3a[2];
        float rb0 = rand3b[0], rb1 = rand3b[1], rb2 = rand3b[2];

        float o0, o1, o2;
        {
            float mn = __fmul_rn(cmin0, cs), mx = __fmul_rn(cmax0, cs);
            float rg = __fsub_rn(mx, mn);
            float A = fmaxf(__fsub_rn(__fsub_rn(14.0f, rg), 0.001f), 0.0f);
            float B = fminf(__fadd_rn(__fsub_rn(14.0f, rg), 0.001f), 0.0f);
            o0 = __fadd_rn(__fadd_rn(-mn, __fmul_rn(A, ra0)), __fmul_rn(B, rb0));
        }
        {
            float mn = __fmul_rn(cmin1, cs), mx = __fmul_rn(cmax1, cs);
            float rg = __fsub_rn(mx, mn);
            float A = fmaxf(__fsub_rn(__fsub_rn(14.0f, rg), 0.001f), 0.0f);
            float B = fminf(__fadd_rn(__fsub_rn(14.0f, rg), 0.001f), 0.0f);
            o1 = __fadd_rn(__fadd_rn(-mn, __fmul_rn(A, ra1)), __fmul_rn(B, rb1));
        }
        {
            float mn = __fmul_rn(cmin2, cs), mx = __fmul_rn(cmax2, cs);
            float rg = __fsub_rn(mx, mn);
            float A = fmaxf(__fsub_rn(__fsub_rn(14.0f, rg), 0.001f), 0.0f);
            float B = fminf(__fadd_rn(__fsub_rn(14.0f, rg), 0.001f), 0.0f);
            o2 = __fadd_rn(__fadd_rn(-mn, __fmul_rn(A, ra2)), __fmul_rn(B, rb2));
        }

        prm[0] = m0; prm[1] = m1; prm[2] = m2;
        prm[3] = cs; prm[4] = o0; prm[5] = o1; prm[6] = o2;

        float* ctr = out + VOUT_OFF + (size_t)c * 3;
        float* szo = out + VOUT_OFF + (size_t)NC * 3 + (size_t)c * 3;
        ctr[0] = __fadd_rn(__fdiv_rn(__fadd_rn(cmax0, cmin0), 2.0f), m0);
        ctr[1] = __fadd_rn(__fdiv_rn(__fadd_rn(cmax1, cmin1), 2.0f), m1);
        ctr[2] = __fadd_rn(__fdiv_rn(__fadd_rn(cmax2, cmin2), 2.0f), m2);
        szo[0] = sz0; szo[1] = sz1; szo[2] = sz2;
    }
    __syncthreads();

    /* voxel id (bit-exact) + near-boundary detection */
    {
        float M0 = prm[0], M1 = prm[1], M2 = prm[2];
        float CS = prm[3], O0 = prm[4], O1 = prm[5], O2 = prm[6];
        float epsw = fmaf(2.5e-4f, CS, 1.2e-5f);
        #pragma unroll
        for (int k = 0; k < 8; ++k) {
            int p = tid + k * TPBA;
            float t0 = __fadd_rn(__fmul_rn(__fsub_rn(ax[p], M0), CS), O0);
            float t1 = __fadd_rn(__fmul_rn(__fsub_rn(ay[p], M1), CS), O1);
            float t2 = __fadd_rn(__fmul_rn(__fsub_rn(az[p], M2), CS), O2);
            int i0 = (int)floorf(t0); i0 = (i0 < 0) ? 0 : ((i0 > FS-1) ? FS-1 : i0);
            int i1 = (int)floorf(t1); i1 = (i1 < 0) ? 0 : ((i1 > FS-1) ? FS-1 : i1);
            int i2 = (int)floorf(t2); i2 = (i2 < 0) ? 0 : ((i2 > FS-1) ? FS-1 : i2);
            int lv = (i0 * FS + i1) * FS + i2;
            vid[p] = (unsigned short)lv;
            atomicAdd(&cnt2[lv >> 1], (lv & 1) ? 0x10000u : 1u);
            #pragma unroll
            for (int dm = 0; dm < 3; ++dm) {
                float t = (dm == 0) ? t0 : (dm == 1) ? t1 : t2;
                float r = rintf(t);
                if (fabsf(t - r) < epsw) {
                    int bi = (int)r;
                    if (bi >= 1 && bi <= 13) {
                        int slot = atomicAdd(nwin, 1);
                        if (slot < WCAP)
                            wlist[slot] = (unsigned)p | ((unsigned)dm << 12)
                                        | ((unsigned)bi << 14) | ((unsigned)lv << 18);
                        break;
                    }
                }
            }
        }
    }
    __syncthreads();

    /* ---- full per-voxel counting sort (staging LDS now dead -> reuse) ---- */
    unsigned int* voxstart = (unsigned int*)(smem + OFF_U);           /* [2745] */
    unsigned int* voxoff   = (unsigned int*)(smem + OFF_U + 11008);   /* [2744] */
    unsigned int* partial  = (unsigned int*)(smem + OFF_U + 22016);   /* [512]  */
    {
        unsigned int s = 0;
        int vlo = tid * 6, vhi = vlo + 6; if (vhi > NVX) vhi = NVX;
        for (int v = vlo; v < vhi; ++v)
            s += (cnt2[v >> 1] >> ((v & 1) * 16)) & 0xffffu;
        partial[tid] = s;
    }
    __syncthreads();
    if (tid == 0) {
        unsigned int run = 0;
        for (int t = 0; t < TPBA; ++t) { unsigned int x = partial[t]; partial[t] = run; run += x; }
        voxstart[NVX] = run;   /* = 4096 */
    }
    __syncthreads();
    {
        unsigned int b2 = partial[tid];
        int vlo = tid * 6, vhi = vlo + 6; if (vhi > NVX) vhi = NVX;
        for (int v = vlo; v < vhi; ++v) {
            voxstart[v] = b2; voxoff[v] = b2;
            b2 += (cnt2[v >> 1] >> ((v & 1) * 16)) & 0xffffu;
        }
    }
    __syncthreads();
    #pragma unroll
    for (int k = 0; k < 8; ++k) {
        int p = tid + k * TPBA;
        int v = vid[p];
        int slot = atomicAdd(&voxoff[v], 1u);
        order[slot] = (unsigned short)p;
    }
    __syncthreads();

    /* dump rec (idx|lv<<20) voxel-sorted + vstart(u16) + windows */
    {
        unsigned int*   wrec = (unsigned int*)(ws + WS_REC)     + (size_t)c * PPC;
        unsigned short* wvst = (unsigned short*)(ws + WS_VST)   + (size_t)c * 2746;
        unsigned int*   ww   = (unsigned int*)(ws + WS_WLIST)   + (size_t)c * WCAP;
        int*            wn   = (int*)(ws + WS_NWIN);
        for (int slot = tid; slot < PPC; slot += TPBA) {
            int p = order[slot];
            wrec[slot] = (unsigned int)cpi[base + p] | ((unsigned int)vid[p] << 20);
        }
        for (int v = tid; v < NVX; v += TPBA) wvst[v] = (unsigned short)voxstart[v];
        if (tid == 0) { wvst[NVX] = (unsigned short)4096; wvst[NVX+1] = (unsigned short)4096; }
        int nw = *nwin; if (nw > WCAP) nw = WCAP;
        for (int w = tid; w < nw; w += TPBA) ww[w] = wlist[w];
        if (tid == 0) wn[c] = nw;
    }
}

/* ===== kernel B: continuous-slot 4-deep pipelined gather, atomic-free, NT flush ===== */
__global__ __launch_bounds__(TPB, 8)
void pg_scatter(const float* __restrict__ feats,
                const char*  __restrict__ ws,
                float*       __restrict__ out)
{
    const int bid = blockIdx.x;          /* 2048 blocks: (cluster, quarter) */
    const int c   = bid >> 2;
    const int q   = bid & 3;
    const int tid = threadIdx.x;
    const int grp = tid >> 3;            /* 0..31 */
    const int ln  = tid & 7;             /* 0..7  */

    const unsigned int*   rec = (const unsigned int*)(ws + WS_REC)   + (size_t)c * PPC;
    const unsigned short* vst = (const unsigned short*)(ws + WS_VST) + (size_t)c * 2746;

    const int vq = NVX / 4;              /* 686 */
    const int v0 = q * vq + (grp * vq) / 32;
    const int v1 = q * vq + ((grp + 1) * vq) / 32;

    nt4* outc = (nt4*)(out + (size_t)c * NVX * CF);

    int v = v0;                          /* next voxel to flush */
    int j  = vst[v0];
    const int a1 = vst[v1];
    float sx = 0.f, sy = 0.f, sz = 0.f, sw = 0.f;

    /* flush all voxels strictly below L (current sums belong to v) */
    #define FLUSH_TO(L)                                                          \
        while (v < (L)) {                                                        \
            float fn = fmaxf((float)(vst[v + 1] - vst[v]), 1.0f);                \
            nt4 o; o.x = sx / fn; o.y = sy / fn; o.z = sz / fn; o.w = sw / fn;   \
            __builtin_nontemporal_store(o, &outc[(size_t)v * 8 + ln]);           \
            sx = sy = sz = sw = 0.f; ++v;                                        \
        }

    /* 4-deep static pipeline over the contiguous slot range */
    while (j + 4 <= a1) {
        unsigned int r0 = rec[j], r1 = rec[j+1], r2 = rec[j+2], r3 = rec[j+3];
        float4 w0 = ((const float4*)(feats + (size_t)(r0 & 0xFFFFFu) * CF))[ln];
        float4 w1 = ((const float4*)(feats + (size_t)(r1 & 0xFFFFFu) * CF))[ln];
        float4 w2 = ((const float4*)(feats + (size_t)(r2 & 0xFFFFFu) * CF))[ln];
        float4 w3 = ((const float4*)(feats + (size_t)(r3 & 0xFFFFFu) * CF))[ln];
        int L0 = (int)(r0 >> 20); FLUSH_TO(L0); sx += w0.x; sy += w0.y; sz += w0.z; sw += w0.w;
        int L1 = (int)(r1 >> 20); FLUSH_TO(L1); sx += w1.x; sy += w1.y; sz += w1.z; sw += w1.w;
        int L2 = (int)(r2 >> 20); FLUSH_TO(L2); sx += w2.x; sy += w2.y; sz += w2.z; sw += w2.w;
        int L3 = (int)(r3 >> 20); FLUSH_TO(L3); sx += w3.x; sy += w3.y; sz += w3.z; sw += w3.w;
        j += 4;
    }
    while (j < a1) {
        unsigned int r0 = rec[j];
        float4 w0 = ((const float4*)(feats + (size_t)(r0 & 0xFFFFFu) * CF))[ln];
        int L0 = (int)(r0 >> 20); FLUSH_TO(L0);
        sx += w0.x; sy += w0.y; sz += w0.z; sw += w0.w;
        ++j;
    }
    FLUSH_TO(v1);
    #undef FLUSH_TO
}

/* ================= kernel C: boundary audit + fractional split ================= */
__global__ __launch_bounds__(64, 1)
void pg_audit(const float* __restrict__ feats,
              const int*   __restrict__ cpi,
              const char*  __restrict__ ws,
              float*       __restrict__ out)
{
    const int c   = blockIdx.x;
    const int tid = threadIdx.x;
    const unsigned short* vst   = (const unsigned short*)(ws + WS_VST) + (size_t)c * 2746;
    const unsigned int*   wlist = (const unsigned int*)(ws + WS_WLIST) + (size_t)c * WCAP;
    int nw = ((const int*)(ws + WS_NWIN))[c]; if (nw > WCAP) nw = WCAP;
    const int base = c * PPC;

    int rew[8]; int nrew = 0;
    for (int e = 0; e < nw; ++e) {
        unsigned int w = wlist[e];
        int p  = (int)(w & 0xFFFu);
        int dm = (int)((w >> 12) & 3u);
        int bi = (int)((w >> 14) & 0xFu);
        int lv = (int)((w >> 18) & 0xFFFu);
        int iz = lv % FS, iy = (lv / FS) % FS, ix = lv / (FS * FS);
        int i  = (dm == 0) ? ix : (dm == 1) ? iy : iz;
        int stride = (dm == 0) ? FS * FS : (dm == 1) ? FS : 1;
        int j = 2 * bi - 1 - i;
        int Alv = lv;
        int Blv = lv + (j - i) * stride;
        bool ok = (j >= 0 && j <= FS - 1);
        for (int r = 0; r < nrew; ++r)
            if (rew[r] == Alv || rew[r] == Blv) ok = false;
        if (!ok) continue;
        int ch = tid & 31;
        float fnA = (float)(vst[Alv + 1] - vst[Alv]);
        float fnB = (float)(vst[Blv + 1] - vst[Blv]);
        float muA = out[((size_t)c * NVX + Alv) * CF + ch];
        float muB = out[((size_t)c * NVX + Blv) * CF + ch];
        float sA = muA * fmaxf(fnA, 1.0f);
        float sB = muB * fmaxf(fnB, 1.0f);
        float fp = feats[(size_t)cpi[base + p] * CF + ch];
        float muAd  = (sA - fp)        / fmaxf(fnA - 1.0f, 1.0f);
        float muBa  = (sB + fp)        / fmaxf(fnB + 1.0f, 1.0f);
        float muAsp = (sA - 0.5f * fp) / fmaxf(fnA - 0.5f, 1.0f);
        float muBsp = (sB + 0.5f * fp) / fmaxf(fnB + 0.5f, 1.0f);
        float ebin  = fmaxf(fabsf(muA - muAd), fabsf(muBa - muB));
        float espl  = fmaxf(fmaxf(fabsf(muAsp - muA), fabsf(muAsp - muAd)),
                            fmaxf(fabsf(muBsp - muB), fabsf(muBsp - muBa)));
        #pragma unroll
        for (int d = 32; d >= 1; d >>= 1) {
            ebin = fmaxf(ebin, __shfl_xor(ebin, d));
            espl = fmaxf(espl, __shfl_xor(espl, d));
        }
        if (ebin > 0.95f && espl < 0.98f) {
            if (tid < 32) out[((size_t)c * NVX + Alv) * CF + ch] = muAsp;
            else          out[((size_t)c * NVX + Blv) * CF + ch] = muBsp;
            if (nrew < 8) rew[nrew++] = Alv;
            if (nrew < 8) rew[nrew++] = Blv;
        }
    }
}

extern "C" void kernel_launch(void* const* d_in, const int* in_sizes, int n_in,
                              void* d_out, int out_size, void* d_ws, size_t ws_size,
                              hipStream_t stream) {
    const float* feats  = (const float*)d_in[0];
    const float* coords = (const float*)d_in[1];
    const int*   cpi    = (const int*)d_in[2];
    const float* r3a    = (const float*)d_in[4];
    const float* r3b    = (const float*)d_in[5];
    float* out = (float*)d_out;
    char*  ws  = (char*)d_ws;

    (void)hipFuncSetAttribute((const void*)pg_stats,
                              hipFuncAttributeMaxDynamicSharedMemorySize, SMEM_A);
    pg_stats<<<dim3(NC), dim3(TPBA), SMEM_A, stream>>>(coords, cpi, r3a, r3b, out, ws);
    pg_scatter<<<dim3(NC * 4), dim3(TPB), 0, stream>>>(feats, ws, out);
    pg_audit<<<dim3(NC), dim3(64), 0, stream>>>(feats, cpi, ws, out);
}